// Round 1
// baseline (472.848 us; speedup 1.0000x reference)
//
#include <hip/hip_runtime.h>

typedef __attribute__((ext_vector_type(8))) __bf16 bf16x8;
typedef __attribute__((ext_vector_type(4))) float f32x4;
typedef unsigned short us;

#define SEQ 2048
#define DIM 1024
#define NH 16
#define HDIM 64

// ---------- helpers ----------
__device__ inline us f2bf(float f) {
    unsigned u = __builtin_bit_cast(unsigned, f);
    u += 0x7FFFu + ((u >> 16) & 1u);   // RNE
    return (us)(u >> 16);
}

// ---------- cast fp32 -> bf16 (4 tensors selectable via blockIdx.y) ----------
__global__ __launch_bounds__(256) void cast_many(
    const float* __restrict__ s0, const float* __restrict__ s1,
    const float* __restrict__ s2, const float* __restrict__ s3,
    us* __restrict__ dst, int n_each)
{
    const float* src = (blockIdx.y == 0) ? s0 : (blockIdx.y == 1) ? s1
                     : (blockIdx.y == 2) ? s2 : s3;
    size_t base = (size_t)blockIdx.y * (size_t)n_each;
    int i = (blockIdx.x * 256 + threadIdx.x) * 4;
    if (i < n_each) {
        float4 v = *(const float4*)(src + i);
        ushort4 o;
        o.x = f2bf(v.x); o.y = f2bf(v.y); o.z = f2bf(v.z); o.w = f2bf(v.w);
        *(ushort4*)(dst + base + i) = o;
    }
}

// ---------- bf16 GEMM: C[M,N] = A[M,K] @ W[N,K]^T + bias ----------
// mode 0: out bf16, split-head [B,H,S,HD]
// mode 1: out bf16, transposed-head [B,H,HD,S]   (for V)
// mode 2: out fp32, row-major [M,N]              (final projection)
#define BM 128
#define BN 128
#define BK 64

__global__ __launch_bounds__(256) void gemm_bf16_tn(
    const us* __restrict__ A, const us* __restrict__ W,
    const float* __restrict__ bias, void* __restrict__ out,
    int M, int N, int K, int mode)
{
    __shared__ us lA[BM * BK];
    __shared__ us lB[BN * BK];

    const int tid  = threadIdx.x;
    const int lane = tid & 63;
    const int w    = tid >> 6;
    const int wm   = w >> 1, wn = w & 1;
    const int m0   = blockIdx.y * BM, n0 = blockIdx.x * BN;
    const int g    = lane >> 4, li = lane & 15;

    const f32x4 fz = {0.f, 0.f, 0.f, 0.f};
    f32x4 acc[4][4];
#pragma unroll
    for (int i = 0; i < 4; i++)
#pragma unroll
        for (int j = 0; j < 4; j++) acc[i][j] = fz;

    for (int k0 = 0; k0 < K; k0 += BK) {
#pragma unroll
        for (int i = 0; i < 4; i++) {
            int v = tid + i * 256;           // vec-of-8 index, 1024 total
            int row = v >> 3, c8 = (v & 7) * 8;
            *(uint4*)&lA[row * BK + c8] =
                *(const uint4*)&A[(size_t)(m0 + row) * K + k0 + c8];
            *(uint4*)&lB[row * BK + c8] =
                *(const uint4*)&W[(size_t)(n0 + row) * K + k0 + c8];
        }
        __syncthreads();
#pragma unroll
        for (int kk = 0; kk < 2; kk++) {
            bf16x8 af[4], bfr[4];
#pragma unroll
            for (int i = 0; i < 4; i++)
                af[i] = *(const bf16x8*)&lA[(wm * 64 + i * 16 + li) * BK + kk * 32 + g * 8];
#pragma unroll
            for (int j = 0; j < 4; j++)
                bfr[j] = *(const bf16x8*)&lB[(wn * 64 + j * 16 + li) * BK + kk * 32 + g * 8];
#pragma unroll
            for (int i = 0; i < 4; i++)
#pragma unroll
                for (int j = 0; j < 4; j++)
                    acc[i][j] = __builtin_amdgcn_mfma_f32_16x16x32_bf16(
                        af[i], bfr[j], acc[i][j], 0, 0, 0);
        }
        __syncthreads();
    }

    // epilogue: C layout col=lane&15, row=(lane>>4)*4+reg  [verified mapping]
    const int r0 = g * 4;
#pragma unroll
    for (int i = 0; i < 4; i++) {
#pragma unroll
        for (int j = 0; j < 4; j++) {
            int col = n0 + wn * 64 + j * 16 + li;
            float bs = bias[col];
#pragma unroll
            for (int r = 0; r < 4; r++) {
                int row = m0 + wm * 64 + i * 16 + r0 + r;
                float val = acc[i][j][r] + bs;
                if (mode == 2) {
                    ((float*)out)[(size_t)row * N + col] = val;
                } else {
                    int b = row >> 11, s = row & (SEQ - 1);
                    int h = col >> 6, hd = col & (HDIM - 1);
                    size_t idx = (mode == 0)
                        ? ((((size_t)b * NH + h) * SEQ + s) * HDIM + hd)
                        : ((((size_t)b * NH + h) * HDIM + hd) * SEQ + s);
                    ((us*)out)[idx] = f2bf(val);
                }
            }
        }
    }
}

// ---------- flash attention: 1 wave per 16-query tile ----------
__global__ __launch_bounds__(256) void attn_fwd(
    const us* __restrict__ Qb, const us* __restrict__ Kb,
    const us* __restrict__ VT, const unsigned char* __restrict__ mask,
    us* __restrict__ out)
{
    __shared__ us lP[4][16 * 40];   // per-wave P tile [16 q][32 keys], stride 40

    const int tid = threadIdx.x;
    const int w = tid >> 6, lane = tid & 63;
    const int tile = blockIdx.x * 4 + w;
    const int bh = tile >> 7;            // 128 q-tiles per (b,h)
    const int qt = tile & 127;
    const int b = bh >> 4, h = bh & 15;
    const int q0 = qt * 16;
    const int g = lane >> 4, li = lane & 15;

    const us* Qp = Qb + ((size_t)bh * SEQ + q0) * HDIM;
    const us* Kp = Kb + (size_t)bh * SEQ * HDIM;
    const us* Vp = VT + (size_t)bh * HDIM * SEQ;
    const unsigned char* mp = mask + (size_t)b * SEQ;

    bf16x8 qf0 = *(const bf16x8*)&Qp[li * HDIM + g * 8];
    bf16x8 qf1 = *(const bf16x8*)&Qp[li * HDIM + 32 + g * 8];

    const f32x4 fz = {0.f, 0.f, 0.f, 0.f};
    f32x4 oacc[4];
    float mrun[4], lrun[4];
#pragma unroll
    for (int i = 0; i < 4; i++) { oacc[i] = fz; mrun[i] = -1e30f; lrun[i] = 0.f; }

    us* myP = lP[w];

    for (int kv = 0; kv < SEQ; kv += 32) {
        f32x4 s0 = fz, s1 = fz;
        {
            bf16x8 ka = *(const bf16x8*)&Kp[(size_t)(kv + li) * HDIM + g * 8];
            bf16x8 kb2 = *(const bf16x8*)&Kp[(size_t)(kv + li) * HDIM + 32 + g * 8];
            s0 = __builtin_amdgcn_mfma_f32_16x16x32_bf16(qf0, ka, s0, 0, 0, 0);
            s0 = __builtin_amdgcn_mfma_f32_16x16x32_bf16(qf1, kb2, s0, 0, 0, 0);
        }
        {
            bf16x8 ka = *(const bf16x8*)&Kp[(size_t)(kv + 16 + li) * HDIM + g * 8];
            bf16x8 kb2 = *(const bf16x8*)&Kp[(size_t)(kv + 16 + li) * HDIM + 32 + g * 8];
            s1 = __builtin_amdgcn_mfma_f32_16x16x32_bf16(qf0, ka, s1, 0, 0, 0);
            s1 = __builtin_amdgcn_mfma_f32_16x16x32_bf16(qf1, kb2, s1, 0, 0, 0);
        }

        float mk0 = mp[kv + li] ? -1e30f : 0.f;
        float mk1 = mp[kv + 16 + li] ? -1e30f : 0.f;

#pragma unroll
        for (int r = 0; r < 4; r++) {
            float v0 = s0[r] * 0.125f + mk0;
            float v1 = s1[r] * 0.125f + mk1;
            float bm = fmaxf(v0, v1);
            bm = fmaxf(bm, __shfl_xor(bm, 1));
            bm = fmaxf(bm, __shfl_xor(bm, 2));
            bm = fmaxf(bm, __shfl_xor(bm, 4));
            bm = fmaxf(bm, __shfl_xor(bm, 8));
            float nm = fmaxf(mrun[r], bm);
            float corr = __expf(mrun[r] - nm);
            float p0 = __expf(v0 - nm), p1 = __expf(v1 - nm);
            float ps = p0 + p1;
            ps += __shfl_xor(ps, 1);
            ps += __shfl_xor(ps, 2);
            ps += __shfl_xor(ps, 4);
            ps += __shfl_xor(ps, 8);
            lrun[r] = lrun[r] * corr + ps;
            mrun[r] = nm;
#pragma unroll
            for (int ni = 0; ni < 4; ni++) oacc[ni][r] *= corr;
            int q = g * 4 + r;
            myP[q * 40 + li]      = f2bf(p0);
            myP[q * 40 + 16 + li] = f2bf(p1);
        }

        // wave-private LDS transpose: P [q][key] -> A-fragment (row = li)
        bf16x8 pf = *(const bf16x8*)&myP[li * 40 + g * 8];
#pragma unroll
        for (int ni = 0; ni < 4; ni++) {
            bf16x8 vf = *(const bf16x8*)&Vp[(size_t)(ni * 16 + li) * SEQ + kv + g * 8];
            oacc[ni] = __builtin_amdgcn_mfma_f32_16x16x32_bf16(pf, vf, oacc[ni], 0, 0, 0);
        }
    }

#pragma unroll
    for (int ni = 0; ni < 4; ni++) {
#pragma unroll
        for (int r = 0; r < 4; r++) {
            float val = oacc[ni][r] / lrun[r];
            out[((size_t)b * SEQ + q0 + g * 4 + r) * DIM + h * HDIM + ni * 16 + li] = f2bf(val);
        }
    }
}

// ---------- launch ----------
extern "C" void kernel_launch(void* const* d_in, const int* in_sizes, int n_in,
                              void* d_out, int out_size, void* d_ws, size_t ws_size,
                              hipStream_t stream)
{
    const float* q  = (const float*)d_in[0];
    const float* k  = (const float*)d_in[1];
    const float* v  = (const float*)d_in[2];
    const unsigned char* mask = (const unsigned char*)d_in[3];
    const float* Wq = (const float*)d_in[4];
    const float* bq = (const float*)d_in[5];
    const float* Wk = (const float*)d_in[6];
    const float* bk = (const float*)d_in[7];
    const float* Wv = (const float*)d_in[8];
    const float* bv = (const float*)d_in[9];
    const float* Wo = (const float*)d_in[10];
    const float* bo = (const float*)d_in[11];

    us* ws  = (us*)d_ws;
    us* xq  = ws;                    // [4096,1024] bf16 each
    us* xk  = ws + 4194304;
    us* xv  = ws + 8388608;
    us* wqb = ws + 12582912;         // [1024,1024] bf16 each
    us* wkb = ws + 13631488;
    us* wvb = ws + 14680064;
    us* wob = ws + 15728640;
    us* Qb  = ws + 16777216;         // [B,H,S,HD] bf16
    us* Kb  = ws + 20971520;         // [B,H,S,HD]
    us* VTb = ws + 25165824;         // [B,H,HD,S]
    us* AO  = ws + 29360128;         // [B*S, D] bf16

    cast_many<<<dim3(4096, 3), 256, 0, stream>>>(q, k, v, q, xq, 4194304);
    cast_many<<<dim3(1024, 4), 256, 0, stream>>>(Wq, Wk, Wv, Wo, wqb, 1048576);

    dim3 ggrid(DIM / BN, (2 * SEQ) / BM);
    gemm_bf16_tn<<<ggrid, 256, 0, stream>>>(xq, wqb, bq, Qb,  2 * SEQ, DIM, DIM, 0);
    gemm_bf16_tn<<<ggrid, 256, 0, stream>>>(xk, wkb, bk, Kb,  2 * SEQ, DIM, DIM, 0);
    gemm_bf16_tn<<<ggrid, 256, 0, stream>>>(xv, wvb, bv, VTb, 2 * SEQ, DIM, DIM, 1);

    attn_fwd<<<dim3(1024), 256, 0, stream>>>(Qb, Kb, VTb, mask, AO);

    gemm_bf16_tn<<<ggrid, 256, 0, stream>>>(AO, wob, bo, (float*)d_out,
                                            2 * SEQ, DIM, DIM, 2);
}

// Round 4
// 320.103 us; speedup vs baseline: 1.4772x; 1.4772x over previous
//
#include <hip/hip_runtime.h>

typedef __attribute__((ext_vector_type(8))) __bf16 bf16x8;
typedef __attribute__((ext_vector_type(4))) float f32x4;
typedef __attribute__((ext_vector_type(16))) float f32x16;
typedef __attribute__((ext_vector_type(4))) unsigned int u32x4;
typedef unsigned short us;

#define SEQ 2048
#define DIM 1024
#define NH 16
#define HDIM 64

// 0.125 * log2(e): folded into Q projection so softmax uses native exp2
#define QSCALE 0.1803368801111204f

__device__ inline us f2bf(float f) {
    unsigned u = __builtin_bit_cast(unsigned, f);
    u += 0x7FFFu + ((u >> 16) & 1u);   // RNE
    return (us)(u >> 16);
}

__device__ inline unsigned sx32(unsigned v) {   // partner-lane (lane^32) value
    return (unsigned)__shfl_xor((int)v, 32);
}

// ---------- cast fp32 -> bf16 ----------
__global__ __launch_bounds__(256) void cast_many(
    const float* __restrict__ s0, const float* __restrict__ s1,
    const float* __restrict__ s2, const float* __restrict__ s3,
    us* __restrict__ dst, int n_each)
{
    const float* src = (blockIdx.y == 0) ? s0 : (blockIdx.y == 1) ? s1
                     : (blockIdx.y == 2) ? s2 : s3;
    size_t base = (size_t)blockIdx.y * (size_t)n_each;
    int i = (blockIdx.x * 256 + threadIdx.x) * 4;
    if (i < n_each) {
        float4 v = *(const float4*)(src + i);
        ushort4 o;
        o.x = f2bf(v.x); o.y = f2bf(v.y); o.z = f2bf(v.z); o.w = f2bf(v.w);
        *(ushort4*)(dst + base + i) = o;
    }
}

// ---------- mask bitpack: mask[2][2048] bytes -> 128 uint32 words ----------
__global__ __launch_bounds__(64) void maskpack(
    const unsigned char* __restrict__ mask, unsigned* __restrict__ mw)
{
    int t = blockIdx.x * 64 + threadIdx.x;   // 0..127
    unsigned wv = 0;
#pragma unroll
    for (int j = 0; j < 32; j++) wv |= (mask[t * 32 + j] ? 1u : 0u) << j;
    mw[t] = wv;
}

// ---------- bf16 GEMM core: C[M,N] = (A[M,K] @ W[N,K]^T + bias) * oscale ----------
// mode 0: out bf16, split-head [B,H,S,HD]
// mode 1: out bf16, transposed-head [B,H,HD,S]   (for V)
// mode 2: out fp32, row-major [M,N]              (final projection)
#define BM 128
#define BN 128
#define BK 64

__device__ __forceinline__ void gemm_core(
    const us* __restrict__ A, const us* __restrict__ W,
    const float* __restrict__ bias, void* __restrict__ out,
    int M, int N, int K, int mode, float oscale)
{
    __shared__ us lA[BM * BK];
    __shared__ us lB[BN * BK];

    const int tid  = threadIdx.x;
    const int lane = tid & 63;
    const int w    = tid >> 6;
    const int wm   = w >> 1, wn = w & 1;
    const int m0   = blockIdx.y * BM, n0 = blockIdx.x * BN;
    const int g    = lane >> 4, li = lane & 15;

    const f32x4 fz = {0.f, 0.f, 0.f, 0.f};
    f32x4 acc[4][4];
#pragma unroll
    for (int i = 0; i < 4; i++)
#pragma unroll
        for (int j = 0; j < 4; j++) acc[i][j] = fz;

    for (int k0 = 0; k0 < K; k0 += BK) {
#pragma unroll
        for (int i = 0; i < 4; i++) {
            int v = tid + i * 256;
            int row = v >> 3, c8 = (v & 7) * 8;
            *(uint4*)&lA[row * BK + c8] =
                *(const uint4*)&A[(size_t)(m0 + row) * K + k0 + c8];
            *(uint4*)&lB[row * BK + c8] =
                *(const uint4*)&W[(size_t)(n0 + row) * K + k0 + c8];
        }
        __syncthreads();
#pragma unroll
        for (int kk = 0; kk < 2; kk++) {
            bf16x8 af[4], bfr[4];
#pragma unroll
            for (int i = 0; i < 4; i++)
                af[i] = *(const bf16x8*)&lA[(wm * 64 + i * 16 + li) * BK + kk * 32 + g * 8];
#pragma unroll
            for (int j = 0; j < 4; j++)
                bfr[j] = *(const bf16x8*)&lB[(wn * 64 + j * 16 + li) * BK + kk * 32 + g * 8];
#pragma unroll
            for (int i = 0; i < 4; i++)
#pragma unroll
                for (int j = 0; j < 4; j++)
                    acc[i][j] = __builtin_amdgcn_mfma_f32_16x16x32_bf16(
                        af[i], bfr[j], acc[i][j], 0, 0, 0);
        }
        __syncthreads();
    }

    const int r0 = g * 4;
#pragma unroll
    for (int i = 0; i < 4; i++) {
#pragma unroll
        for (int j = 0; j < 4; j++) {
            int col = n0 + wn * 64 + j * 16 + li;
            float bs = bias[col];
#pragma unroll
            for (int r = 0; r < 4; r++) {
                int row = m0 + wm * 64 + i * 16 + r0 + r;
                float val = (acc[i][j][r] + bs) * oscale;
                if (mode == 2) {
                    ((float*)out)[(size_t)row * N + col] = val;
                } else {
                    int b = row >> 11, s = row & (SEQ - 1);
                    int h = col >> 6, hd = col & (HDIM - 1);
                    size_t idx = (mode == 0)
                        ? ((((size_t)b * NH + h) * SEQ + s) * HDIM + hd)
                        : ((((size_t)b * NH + h) * HDIM + hd) * SEQ + s);
                    ((us*)out)[idx] = f2bf(val);
                }
            }
        }
    }
}

__global__ __launch_bounds__(256) void gemm_qkv(
    const us* __restrict__ xq, const us* __restrict__ xk, const us* __restrict__ xv,
    const us* __restrict__ wq, const us* __restrict__ wk, const us* __restrict__ wv,
    const float* __restrict__ bq, const float* __restrict__ bk, const float* __restrict__ bv,
    us* __restrict__ Qb, us* __restrict__ Kb, us* __restrict__ VTb)
{
    int z = blockIdx.z;
    if (z == 0)      gemm_core(xq, wq, bq, Qb,  2 * SEQ, DIM, DIM, 0, QSCALE);
    else if (z == 1) gemm_core(xk, wk, bk, Kb,  2 * SEQ, DIM, DIM, 0, 1.0f);
    else             gemm_core(xv, wv, bv, VTb, 2 * SEQ, DIM, DIM, 1, 1.0f);
}

__global__ __launch_bounds__(256) void gemm_one(
    const us* __restrict__ A, const us* __restrict__ W,
    const float* __restrict__ bias, float* __restrict__ out)
{
    gemm_core(A, W, bias, out, 2 * SEQ, DIM, DIM, 2, 1.0f);
}

// ---------- attention: 1 wave per 32-query tile, swapped-operand 32x32 MFMA ----------
// S^T = mfma(K,Q): lane owns q=lane&31; 16 scores at key=(r&3)+8*(r>>2)+4*hi.
// O^T = mfma(V^T,P^T): lane owns O column for its q -> softmax state fully lane-local.
// Cross-half exchange via __shfl_xor(.,32) (ds_bpermute -- defined semantics).
__global__ __launch_bounds__(256) void attn_fwd2(
    const us* __restrict__ Qb, const us* __restrict__ Kb,
    const us* __restrict__ VT, const unsigned* __restrict__ mw,
    us* __restrict__ out)
{
    const int tid  = threadIdx.x;
    const int w    = tid >> 6, lane = tid & 63;
    const int tile = blockIdx.x * 4 + w;         // 2048 tiles
    const int bh   = tile >> 6, qt = tile & 63;  // 64 q-tiles per (b,h)
    const int b    = bh >> 4, h = bh & 15;
    const int q0   = qt * 32;
    const int ql   = lane & 31, hi = lane >> 5;

    const us* Qp  = Qb + (((size_t)bh * SEQ) + q0 + ql) * HDIM + hi * 8;
    const us* Kp  = Kb + ((size_t)bh * SEQ + ql) * HDIM + hi * 8;
    const us* Vp0 = VT + ((size_t)bh * HDIM + ql) * SEQ + hi * 8;
    const us* Vp1 = Vp0 + 32 * SEQ;

    bf16x8 qf[4];
#pragma unroll
    for (int t = 0; t < 4; t++) qf[t] = *(const bf16x8*)(Qp + t * 16);

    f32x16 o0 = {0,0,0,0,0,0,0,0,0,0,0,0,0,0,0,0};
    f32x16 o1 = {0,0,0,0,0,0,0,0,0,0,0,0,0,0,0,0};
    const f32x16 z16 = {0,0,0,0,0,0,0,0,0,0,0,0,0,0,0,0};
    float mrun = -1e30f, lrun = 0.f;

    bf16x8 kf[4];
#pragma unroll
    for (int t = 0; t < 4; t++) kf[t] = *(const bf16x8*)(Kp + t * 16);

    for (int kv = 0; kv < SEQ; kv += 32) {
        bf16x8 vf0[2], vf1[2];
#pragma unroll
        for (int t = 0; t < 2; t++) {
            vf0[t] = *(const bf16x8*)(Vp0 + kv + t * 16);
            vf1[t] = *(const bf16x8*)(Vp1 + kv + t * 16);
        }

        f32x16 s = z16;
#pragma unroll
        for (int t = 0; t < 4; t++)
            s = __builtin_amdgcn_mfma_f32_32x32x16_bf16(kf[t], qf[t], s, 0, 0, 0);

        if (kv + 32 < SEQ) {                      // prefetch next K tile
            const us* Kn = Kp + (size_t)(kv + 32) * HDIM;
#pragma unroll
            for (int t = 0; t < 4; t++) kf[t] = *(const bf16x8*)(Kn + t * 16);
        }

        unsigned m32 = (unsigned)__builtin_amdgcn_readfirstlane(
            (int)mw[b * 64 + (kv >> 5)]);

        float pmax = s[0];
#pragma unroll
        for (int r = 1; r < 16; r++) pmax = fmaxf(pmax, s[r]);
        pmax = fmaxf(pmax, __shfl_xor(pmax, 32));

        float nm   = fmaxf(mrun, pmax);
        float corr = __builtin_amdgcn_exp2f(mrun - nm);
        float p[16];
#pragma unroll
        for (int r = 0; r < 16; r++) p[r] = __builtin_amdgcn_exp2f(s[r] - nm);
        if (m32) {   // key-padding mask: zero masked columns post-exp
            unsigned ms = hi ? (m32 >> 4) : m32;
#pragma unroll
            for (int r = 0; r < 16; r++)
                if ((ms >> ((r & 3) + 8 * (r >> 2))) & 1) p[r] = 0.f;
        }
        float ps = 0.f;
#pragma unroll
        for (int r = 0; r < 16; r++) ps += p[r];
        ps += __shfl_xor(ps, 32);

        lrun = lrun * corr + ps;
        mrun = nm;
#pragma unroll
        for (int j = 0; j < 16; j++) { o0[j] *= corr; o1[j] *= corr; }

        // pack P -> bf16 B-fragments.
        // pw layout per lane (hi=0): pw0=(k0,k1) pw1=(k2,k3) pw2=(k8,k9)  pw3=(k10,k11)
        //                            pw4=(k16,k17) pw5=(k18,k19) pw6=(k24,k25) pw7=(k26,k27)
        // (hi=1 lanes hold the +4 keys: pw0=(k4,k5) pw2=(k12,k13) ...)
        // B-fragment element j must hold key 8*hi + j (within each 16-key block):
        //   hi=0: [own0, own1, part0, part1]   (partner=lane+32 has keys 4..7 in pw0,pw1)
        //   hi=1: [part2, part3, own2, own3]   (partner=lane-32 has keys 8..11 in pw2,pw3)
        unsigned pw[8];
#pragma unroll
        for (int j = 0; j < 8; j++)
            asm("v_cvt_pk_bf16_f32 %0, %1, %2"
                : "=v"(pw[j]) : "v"(p[2 * j]), "v"(p[2 * j + 1]));

        unsigned x0 = sx32(pw[0]), x1 = sx32(pw[1]), x2 = sx32(pw[2]), x3 = sx32(pw[3]);
        unsigned x4 = sx32(pw[4]), x5 = sx32(pw[5]), x6 = sx32(pw[6]), x7 = sx32(pw[7]);

        u32x4 t0, t1;
        t0.x = hi ? x2    : pw[0];
        t0.y = hi ? x3    : pw[1];
        t0.z = hi ? pw[2] : x0;
        t0.w = hi ? pw[3] : x1;
        t1.x = hi ? x6    : pw[4];
        t1.y = hi ? x7    : pw[5];
        t1.z = hi ? pw[6] : x4;
        t1.w = hi ? pw[7] : x5;
        bf16x8 pa0 = __builtin_bit_cast(bf16x8, t0);
        bf16x8 pa1 = __builtin_bit_cast(bf16x8, t1);

        o0 = __builtin_amdgcn_mfma_f32_32x32x16_bf16(vf0[0], pa0, o0, 0, 0, 0);
        o0 = __builtin_amdgcn_mfma_f32_32x32x16_bf16(vf0[1], pa1, o0, 0, 0, 0);
        o1 = __builtin_amdgcn_mfma_f32_32x32x16_bf16(vf1[0], pa0, o1, 0, 0, 0);
        o1 = __builtin_amdgcn_mfma_f32_32x32x16_bf16(vf1[1], pa1, o1, 0, 0, 0);
    }

    float inv = __builtin_amdgcn_rcpf(lrun);
    us* op = out + ((size_t)b * SEQ + q0 + ql) * DIM + h * HDIM + 4 * hi;
#pragma unroll
    for (int g2 = 0; g2 < 4; g2++) {
        ushort4 v0, v1;
        v0.x = f2bf(o0[4 * g2 + 0] * inv); v0.y = f2bf(o0[4 * g2 + 1] * inv);
        v0.z = f2bf(o0[4 * g2 + 2] * inv); v0.w = f2bf(o0[4 * g2 + 3] * inv);
        v1.x = f2bf(o1[4 * g2 + 0] * inv); v1.y = f2bf(o1[4 * g2 + 1] * inv);
        v1.z = f2bf(o1[4 * g2 + 2] * inv); v1.w = f2bf(o1[4 * g2 + 3] * inv);
        *(ushort4*)(op + 8 * g2)      = v0;   // d = 8*g2 + 4*hi + 0..3
        *(ushort4*)(op + 32 + 8 * g2) = v1;   // d = 32 + ...
    }
}

// ---------- launch ----------
extern "C" void kernel_launch(void* const* d_in, const int* in_sizes, int n_in,
                              void* d_out, int out_size, void* d_ws, size_t ws_size,
                              hipStream_t stream)
{
    const float* q  = (const float*)d_in[0];
    const float* k  = (const float*)d_in[1];
    const float* v  = (const float*)d_in[2];
    const unsigned char* mask = (const unsigned char*)d_in[3];
    const float* Wq = (const float*)d_in[4];
    const float* bq = (const float*)d_in[5];
    const float* Wk = (const float*)d_in[6];
    const float* bk = (const float*)d_in[7];
    const float* Wv = (const float*)d_in[8];
    const float* bv = (const float*)d_in[9];
    const float* Wo = (const float*)d_in[10];
    const float* bo = (const float*)d_in[11];

    us* ws  = (us*)d_ws;
    us* xq  = ws;                    // [4096,1024] bf16 each
    us* xk  = ws + 4194304;
    us* xv  = ws + 8388608;
    us* wqb = ws + 12582912;         // [1024,1024] bf16 each
    us* wkb = ws + 13631488;
    us* wvb = ws + 14680064;
    us* wob = ws + 15728640;
    us* Qb  = ws + 16777216;         // [B,H,S,HD] bf16 (pre-scaled by QSCALE)
    us* Kb  = ws + 20971520;         // [B,H,S,HD]
    us* VTb = ws + 25165824;         // [B,H,HD,S]
    us* AO  = ws + 29360128;         // [B*S, D] bf16
    unsigned* mwords = (unsigned*)(ws + 33554432);   // 128 words

    cast_many<<<dim3(4096, 3), 256, 0, stream>>>(q, k, v, q, xq, 4194304);
    cast_many<<<dim3(1024, 4), 256, 0, stream>>>(Wq, Wk, Wv, Wo, wqb, 1048576);
    maskpack<<<dim3(2), 64, 0, stream>>>(mask, mwords);

    gemm_qkv<<<dim3(DIM / BN, (2 * SEQ) / BM, 3), 256, 0, stream>>>(
        xq, xk, xv, wqb, wkb, wvb, bq, bk, bv, Qb, Kb, VTb);

    attn_fwd2<<<dim3(512), 256, 0, stream>>>(Qb, Kb, VTb, mwords, AO);

    gemm_one<<<dim3(DIM / BN, (2 * SEQ) / BM), 256, 0, stream>>>(AO, wob, bo, (float*)d_out);
}